// Round 7
// baseline (182.576 us; speedup 1.0000x reference)
//
#include <hip/hip_runtime.h>

// AnomalyAttention forward, MI355X gfx950.
// B=8, N=1024, D=1024. Out = [Z (8*1024*1024 f32), P (8*1024*1024 f32)].
// Round 7: dispatch-graph surgery on round-6 (verified GEMM body unchanged):
//   prep   = cvt_x+sigma+rowsum | Wq/Wk copy | Wv transpose   (768 blocks)
//   gvt    = G gemm (32 blk) | VT gemm (256 blk) | batch_reduce (8 blk)
//   xq     = x*(Wq Wk^T)            (256 blk)
//   scores = xq x^T / 32            (256 blk, one batch per XCD)
//   softmax over batch              (4096 blk)
//   svp    = Z = S V (256 blk) | prior P write (128 filler blk)
// 6 dispatches total. Workspace ~59 MB; scores scratch overlays Pout.

typedef __attribute__((ext_vector_type(8))) short bf16x8;
typedef __attribute__((ext_vector_type(4))) float f32x4;
typedef unsigned short ushort_t;

#define DI __device__ __forceinline__

constexpr long NN = 1024L * 1024L;
constexpr long ND = 1024L * 1024L;

DI ushort_t f2bf(float f) {  // round-to-nearest-even f32 -> bf16 bits
    unsigned int u = __float_as_uint(f);
    u = u + 0x7fffu + ((u >> 16) & 1u);
    return (ushort_t)(u >> 16);
}

// ---------------------------------------------------------------------------
// Pipelined GEMM body (identical sync structure to verified round-3/6 kernel):
// C[M,N] tile = A[M,K=1024] * Bt[N,K=1024]^T, bf16 in, fp32 acc.
// Tile 128x256, BK=64, 8 waves (2M x 4N), per-wave 64x64 (4x4 16x16x32 frags).
// LDS: 3 buffers, XOR-swizzled (byte ^= (row&7)<<4); linear gload_lds dest +
// inverse-swizzled global source. 2 phases/K-tile, prefetch dist 2, vmcnt(6).
// ---------------------------------------------------------------------------
template <int OUT_BF16>
DI void g3b_body(const ushort_t* __restrict__ Ab, const ushort_t* __restrict__ Bb,
                 void* __restrict__ Cb, int ldA, int ldB, int ldC,
                 float scale, int bx, int by, ushort_t* lds)
{
    constexpr int BUF   = 24576;   // per buf: A 8192 + B 16384 ushorts
    constexpr int B_OFF = 8192;

    const int tid  = threadIdx.x;
    const int wave = tid >> 6;
    const int lane = tid & 63;
    const int wm   = wave >> 2;   // 0..1
    const int wn   = wave & 3;    // 0..3
    const int gm   = bx * 128;
    const int gn   = by * 256;

    // staging: thread t loads 16B; row in 64-row half = tid>>3,
    // swizzled source col chunk = (tid&7) ^ (row&7)
    const int srow = tid >> 3;
    const int scol = 8 * ((tid & 7) ^ (srow & 7));
    const int sdst = wave * 512;   // wave-uniform LDS dest offset (ushorts)

    auto stageA = [&](int t, int d, int h) {
        const ushort_t* src = Ab + (long)(gm + h * 64 + srow) * ldA + t * 64 + scol;
        __builtin_amdgcn_global_load_lds(
            (const __attribute__((address_space(1))) void*)src,
            (__attribute__((address_space(3))) void*)(&lds[d * BUF + h * 4096 + sdst]),
            16, 0, 0);
    };
    auto stageB = [&](int t, int d, int h, int j) {
        const ushort_t* src = Bb + (long)(gn + h * 128 + j * 64 + srow) * ldB + t * 64 + scol;
        __builtin_amdgcn_global_load_lds(
            (const __attribute__((address_space(1))) void*)src,
            (__attribute__((address_space(3))) void*)(&lds[d * BUF + B_OFF + h * 8192 + j * 4096 + sdst]),
            16, 0, 0);
    };

    // fragment reads: row = base + (lane&15); swizzle uses row&7 == lane&7
    const int arow = wm * 64 + (lane & 15);
    const int brow = wn * 64 + (lane & 15);
    const int cs0 = (((lane >> 4) * 16) ^ ((lane & 7) << 4)) >> 1;        // ushorts
    const int cs1 = ((64 + (lane >> 4) * 16) ^ ((lane & 7) << 4)) >> 1;

    f32x4 acc[4][4];
#pragma unroll
    for (int m = 0; m < 4; ++m)
#pragma unroll
        for (int n = 0; n < 4; ++n) acc[m][n] = (f32x4){0.f, 0.f, 0.f, 0.f};

    // prologue: tile0 -> buf0, tile1 -> buf1 (6 loads each)
    stageA(0, 0, 0); stageA(0, 0, 1);
    stageB(0, 0, 0, 0); stageB(0, 0, 0, 1); stageB(0, 0, 1, 0); stageB(0, 0, 1, 1);
    stageA(1, 1, 0); stageA(1, 1, 1);
    stageB(1, 1, 0, 0); stageB(1, 1, 0, 1); stageB(1, 1, 1, 0); stageB(1, 1, 1, 1);
    asm volatile("s_waitcnt vmcnt(6)" ::: "memory");   // tile0 resident
    __builtin_amdgcn_s_barrier();
    __builtin_amdgcn_sched_barrier(0);

    int cur = 0;
    for (int t = 0; t < 16; ++t) {
        const int nxt = (cur == 0) ? 2 : cur - 1;      // (t+2)%3
        const ushort_t* la = &lds[cur * BUF];
        const ushort_t* lb = &lds[cur * BUF + B_OFF];

        bf16x8 a[2][4], b[2][4];
        // ---- phase 1 ----
#pragma unroll
        for (int mi = 0; mi < 4; ++mi) {
            a[0][mi] = *(const bf16x8*)&la[(arow + mi * 16) * 64 + cs0];
            a[1][mi] = *(const bf16x8*)&la[(arow + mi * 16) * 64 + cs1];
        }
#pragma unroll
        for (int ni = 0; ni < 2; ++ni) {
            b[0][ni] = *(const bf16x8*)&lb[(brow + ni * 16) * 64 + cs0];
            b[1][ni] = *(const bf16x8*)&lb[(brow + ni * 16) * 64 + cs1];
        }
        if (t < 14) {
            stageB(t + 2, nxt, 0, 0); stageB(t + 2, nxt, 0, 1);
            stageB(t + 2, nxt, 1, 0); stageB(t + 2, nxt, 1, 1);
        }
        __builtin_amdgcn_s_barrier();
        asm volatile("s_waitcnt lgkmcnt(0)" ::: "memory");
        __builtin_amdgcn_sched_barrier(0);
        __builtin_amdgcn_s_setprio(1);
#pragma unroll
        for (int mi = 0; mi < 4; ++mi)
#pragma unroll
            for (int ni = 0; ni < 2; ++ni) {
                acc[mi][ni] = __builtin_amdgcn_mfma_f32_16x16x32_bf16(a[0][mi], b[0][ni], acc[mi][ni], 0, 0, 0);
                acc[mi][ni] = __builtin_amdgcn_mfma_f32_16x16x32_bf16(a[1][mi], b[1][ni], acc[mi][ni], 0, 0, 0);
            }
        __builtin_amdgcn_s_setprio(0);
        __builtin_amdgcn_s_barrier();
        __builtin_amdgcn_sched_barrier(0);

        // ---- phase 2 ----
#pragma unroll
        for (int ni = 2; ni < 4; ++ni) {
            b[0][ni] = *(const bf16x8*)&lb[(brow + ni * 16) * 64 + cs0];
            b[1][ni] = *(const bf16x8*)&lb[(brow + ni * 16) * 64 + cs1];
        }
        if (t < 14) { stageA(t + 2, nxt, 0); stageA(t + 2, nxt, 1); }
        __builtin_amdgcn_s_barrier();
        asm volatile("s_waitcnt lgkmcnt(0)" ::: "memory");
        if (t < 14) asm volatile("s_waitcnt vmcnt(6)" ::: "memory");  // tile t+1 landed
        else        asm volatile("s_waitcnt vmcnt(0)" ::: "memory");
        __builtin_amdgcn_sched_barrier(0);
        __builtin_amdgcn_s_setprio(1);
#pragma unroll
        for (int mi = 0; mi < 4; ++mi)
#pragma unroll
            for (int ni = 2; ni < 4; ++ni) {
                acc[mi][ni] = __builtin_amdgcn_mfma_f32_16x16x32_bf16(a[0][mi], b[0][ni], acc[mi][ni], 0, 0, 0);
                acc[mi][ni] = __builtin_amdgcn_mfma_f32_16x16x32_bf16(a[1][mi], b[1][ni], acc[mi][ni], 0, 0, 0);
            }
        __builtin_amdgcn_s_setprio(0);
        __builtin_amdgcn_s_barrier();
        __builtin_amdgcn_sched_barrier(0);

        cur = (cur == 2) ? 0 : cur + 1;
    }

    // epilogue. C/D layout (verified): col = lane&15, row = (lane>>4)*4 + r
    if (OUT_BF16) {
        ushort_t* el = lds;          // [128][256] ushort = 64 KB
#pragma unroll
        for (int mi = 0; mi < 4; ++mi)
#pragma unroll
            for (int ni = 0; ni < 4; ++ni)
#pragma unroll
                for (int r = 0; r < 4; ++r)
                    el[(wm * 64 + mi * 16 + (lane >> 4) * 4 + r) * 256 +
                       wn * 64 + ni * 16 + (lane & 15)] = f2bf(acc[mi][ni][r] * scale);
        __builtin_amdgcn_s_barrier();
        ushort_t* C = (ushort_t*)Cb;
#pragma unroll
        for (int rr = 0; rr < 8; ++rr) {
            const int row = rr * 16 + (tid >> 5);
            const int col = (tid & 31) * 8;
            *(bf16x8*)&C[(long)(gm + row) * ldC + gn + col] =
                *(const bf16x8*)&el[row * 256 + col];
        }
    } else {
        // two 64-row halves staged through LDS for coalesced float4 stores
        float* el = (float*)lds;     // [64][256] f32 = 64 KB
        float* C  = (float*)Cb;
#pragma unroll
        for (int h = 0; h < 2; ++h) {
            if (wm == h) {
#pragma unroll
                for (int mi = 0; mi < 4; ++mi)
#pragma unroll
                    for (int ni = 0; ni < 4; ++ni)
#pragma unroll
                        for (int r = 0; r < 4; ++r)
                            el[(mi * 16 + (lane >> 4) * 4 + r) * 256 +
                               wn * 64 + ni * 16 + (lane & 15)] = acc[mi][ni][r] * scale;
            }
            __builtin_amdgcn_s_barrier();
#pragma unroll
            for (int i = 0; i < 8; ++i) {
                const int cc  = i * 512 + tid;      // 16B chunk id, 0..4095
                const int row = cc >> 6;
                const int c4  = (cc & 63) * 4;
                *(float4*)&C[(long)(gm + h * 64 + row) * ldC + gn + c4] =
                    *(const float4*)&el[row * 256 + c4];
            }
            __builtin_amdgcn_s_barrier();
        }
    }
}

// standalone GEMM with bijective XCD-chunk swizzle decode
template <int OUT_BF16>
__global__ __launch_bounds__(512, 2)
void gemm3b(const ushort_t* __restrict__ A, const ushort_t* __restrict__ B,
            void* __restrict__ Cout, int ldA, int ldB, int ldC,
            long sA, long sB, long sC, float scale,
            int n0, int n1, int xfirst)
{
    __shared__ ushort_t lds[3 * 24576];
    const int total = gridDim.x;
    const int lin   = blockIdx.x;
    const int swz   = (lin & 7) * (total >> 3) + (lin >> 3);
    const int c0    = swz % n0;
    const int rem   = swz / n0;
    const int c1    = rem % n1;
    const int bz    = rem / n1;
    const int bx    = xfirst ? c0 : c1;
    const int by    = xfirst ? c1 : c0;
    void* Cb = OUT_BF16 ? (void*)((ushort_t*)Cout + (long)bz * sC)
                        : (void*)((float*)Cout + (long)bz * sC);
    g3b_body<OUT_BF16>(A + (long)bz * sA, B + (long)bz * sB, Cb,
                       ldA, ldB, ldC, scale, bx, by, lds);
}

// ---------------------------------------------------------------------------
// prep: role-split 768 blocks x 256 thr.
//   blocks 0..511:   x -> bf16 + sigma + prior rowsum (16 rows each)
//   blocks 512..767: Wv transpose tile (1 of 256) + Wq/Wk bf16 copy chunk
// ---------------------------------------------------------------------------
__global__ __launch_bounds__(256)
void prep(const float* __restrict__ x, const float* __restrict__ Ws,
          const float* __restrict__ Wq, const float* __restrict__ Wk,
          const float* __restrict__ Wv,
          ushort_t* __restrict__ xh, float* __restrict__ sigma,
          float* __restrict__ rowsum,
          ushort_t* __restrict__ Wqh, ushort_t* __restrict__ Wkh,
          ushort_t* __restrict__ WvT)
{
    __shared__ float s[64][65];
    const int blk = blockIdx.x;
    if (blk < 512) {
        const int lane = threadIdx.x & 63;
#pragma unroll
        for (int it = 0; it < 4; ++it) {
            const int row = blk * 16 + it * 4 + (threadIdx.x >> 6);
            const float* xr = x + (long)row * 1024;
            float dot = 0.f;
#pragma unroll
            for (int c = 0; c < 4; ++c) {
                const int i = c * 256 + lane * 4;
                float4 v = *(const float4*)(xr + i);
                float4 w = *(const float4*)(Ws + i);
                dot += v.x * w.x + v.y * w.y + v.z * w.z + v.w * w.w;
                ushort4 o;
                o.x = f2bf(v.x); o.y = f2bf(v.y); o.z = f2bf(v.z); o.w = f2bf(v.w);
                *(ushort4*)(xh + (long)row * 1024 + i) = o;
            }
#pragma unroll
            for (int o = 32; o; o >>= 1) dot += __shfl_down(dot, o);
            float sg;
            if (lane == 0) {
                float t = 1.f / (1.f + __expf(-5.f * dot)) + 1e-5f;
                sg = exp2f(t * 1.5849625007211562f) - 1.f;   // 3^t - 1
            }
            sg = __shfl(sg, 0);
            const int i = row & 1023;
            const float c = -0.5f / (sg * sg);
            float a = 0.f;
            for (int j = lane; j < 1024; j += 64) {
                float d = (float)(i - j);
                a += __expf(c * d * d);
            }
#pragma unroll
            for (int o = 32; o; o >>= 1) a += __shfl_down(a, o);
            if (lane == 0) {
                sigma[row]  = sg;
                rowsum[row] = (0.3989422804014327f / sg) * a;
            }
        }
    } else {
        const int bi = blk - 512;               // 0..255
        // Wv transpose tile (64x64)
        const int tr = (bi >> 4) * 64, tc = (bi & 15) * 64;
        const int t = threadIdx.x;
        const int r = t >> 4, c4 = (t & 15) * 4;
#pragma unroll
        for (int rr = r; rr < 64; rr += 16) {
            float4 v = *(const float4*)(Wv + (long)(tr + rr) * 1024 + tc + c4);
            s[rr][c4] = v.x; s[rr][c4 + 1] = v.y; s[rr][c4 + 2] = v.z; s[rr][c4 + 3] = v.w;
        }
        __syncthreads();
#pragma unroll
        for (int rr = r; rr < 64; rr += 16) {
            ushort4 o;
            o.x = f2bf(s[c4][rr]);     o.y = f2bf(s[c4 + 1][rr]);
            o.z = f2bf(s[c4 + 2][rr]); o.w = f2bf(s[c4 + 3][rr]);
            *(ushort4*)(WvT + (long)(tc + rr) * 1024 + tr + c4) = o;
        }
        // Wq / Wk straight bf16 copy: 4096 f32 each per block
#pragma unroll
        for (int it = 0; it < 4; ++it) {
            const long i = (long)bi * 4096 + it * 1024 + t * 4;
            float4 vq = *(const float4*)(Wq + i);
            float4 vk = *(const float4*)(Wk + i);
            ushort4 oq, ok;
            oq.x = f2bf(vq.x); oq.y = f2bf(vq.y); oq.z = f2bf(vq.z); oq.w = f2bf(vq.w);
            ok.x = f2bf(vk.x); ok.y = f2bf(vk.y); ok.z = f2bf(vk.z); ok.w = f2bf(vk.w);
            *(ushort4*)(Wqh + i) = oq;
            *(ushort4*)(Wkh + i) = ok;
        }
    }
}

// ---------------------------------------------------------------------------
// gvt: 296 blocks x 512 thr.
//   lin 0..255:   VT = Wv^T x^T   (bx in [0,8), by in [0,32), ldC 8192)
//   lin 256..287: G  = Wk Wq^T    (bx in [0,8), by in [0,4))
//   lin 288..295: batch_reduce b = lin-288
// ---------------------------------------------------------------------------
__global__ __launch_bounds__(512, 2)
void gvt(const ushort_t* __restrict__ WvT, const ushort_t* __restrict__ xh,
         ushort_t* __restrict__ VTall,
         const ushort_t* __restrict__ Wkh, const ushort_t* __restrict__ Wqh,
         ushort_t* __restrict__ G,
         const float* __restrict__ rowsum, float* __restrict__ batchsum)
{
    __shared__ ushort_t lds[3 * 24576];
    const int lin = blockIdx.x;
    if (lin < 256) {
        // VT: chunked swizzle over 256 blocks, bx fastest
        const int swz = (lin & 7) * 32 + (lin >> 3);
        const int bx  = swz & 7;          // 8 M-tiles
        const int by  = swz >> 3;         // 32 N-tiles
        g3b_body<1>(WvT, xh, VTall, 1024, 1024, 8192, 1.f, bx, by, lds);
    } else if (lin < 288) {
        const int l2  = lin - 256;        // 0..31
        const int swz = (l2 & 7) * 4 + (l2 >> 3);
        const int bx  = swz & 7;          // 8 M-tiles
        const int by  = swz >> 3;         // 4 N-tiles
        g3b_body<1>(Wkh, Wqh, G, 1024, 1024, 1024, 1.f, bx, by, lds);
    } else {
        __shared__ float sr[512];
        const int b = lin - 288, t = threadIdx.x;
        float a = (t < 1024 - 512) ? 0.f : 0.f;
        a = rowsum[b * 1024 + t] + rowsum[b * 1024 + 512 + t];
        sr[t] = a; __syncthreads();
        for (int o = 256; o; o >>= 1) { if (t < o) sr[t] += sr[t + o]; __syncthreads(); }
        if (t == 0) batchsum[b] = sr[0];
    }
}

// softmax over batch dim (8 values, stride NN)
__global__ void softmax_batch(const float* __restrict__ scores, ushort_t* __restrict__ S)
{
    const long idx = (long)blockIdx.x * 256 + threadIdx.x;
    float v[8], m = -1e30f;
#pragma unroll
    for (int b = 0; b < 8; ++b) { v[b] = scores[(long)b * NN + idx]; m = fmaxf(m, v[b]); }
    float sum = 0.f;
#pragma unroll
    for (int b = 0; b < 8; ++b) { v[b] = __expf(v[b] - m); sum += v[b]; }
    const float inv = 1.f / sum;
#pragma unroll
    for (int b = 0; b < 8; ++b) S[(long)b * NN + idx] = f2bf(v[b] * inv);
}

// ---------------------------------------------------------------------------
// svp: 384 blocks x 512 thr.
//   lin 0..255:   Z = S V (one batch per XCD chunk)
//   lin 256..383: prior P write (grid-stride filler; Pout scores already
//                 consumed by softmax in the previous dispatch)
// ---------------------------------------------------------------------------
__global__ __launch_bounds__(512, 2)
void svp(const ushort_t* __restrict__ S, const ushort_t* __restrict__ VTall,
         float* __restrict__ Z, const float* __restrict__ sigma,
         const float* __restrict__ batchsum, float* __restrict__ P)
{
    __shared__ ushort_t lds[3 * 24576];
    const int lin = blockIdx.x;
    if (lin < 256) {
        const int swz = (lin & 7) * 32 + (lin >> 3);
        const int bx  = swz & 7;          // 8 M-tiles
        const int by  = (swz >> 3) & 3;   // 4 N-tiles
        const int bz  = swz >> 5;         // batch = XCD
        g3b_body<0>(S + (long)bz * NN, VTall + bz * 1024,
                    (void*)(Z + (long)bz * ND), 1024, 8192, 1024,
                    1.f, bx, by, lds);
    } else {
        const long stride = 128L * 512;
        for (long idx = (long)(lin - 256) * 512 + threadIdx.x; idx < 8 * NN; idx += stride) {
            const int b   = (int)(idx >> 20);
            const int rem = (int)(idx & (NN - 1));
            const int i = rem >> 10;
            const int j = rem & 1023;
            const float sg = sigma[(b << 10) + i];
            const float d = (float)(i - j);
            P[idx] = (0.3989422804014327f / sg) *
                     __expf((-0.5f / (sg * sg)) * d * d) / batchsum[b];
        }
    }
}

// ---------------------------------------------------------------------------
extern "C" void kernel_launch(void* const* d_in, const int* in_sizes, int n_in,
                              void* d_out, int out_size, void* d_ws, size_t ws_size,
                              hipStream_t stream)
{
    const float* x  = (const float*)d_in[0];
    const float* Wq = (const float*)d_in[1];
    const float* Wk = (const float*)d_in[2];
    const float* Wv = (const float*)d_in[3];
    const float* Ws = (const float*)d_in[4];
    float* Zout = (float*)d_out;
    float* Pout = Zout + 8 * ND;

    char* base = (char*)d_ws;
    size_t off = 0;
    auto alloc = [&](size_t bytes) {
        void* p = base + off;
        off = (off + bytes + 255) & ~(size_t)255;
        return p;
    };
    ushort_t* xh    = (ushort_t*)alloc(8192L * 1024 * 2);   // 16.78 MB
    ushort_t* Wqh   = (ushort_t*)alloc(NN * 2);             //  2.10 MB
    ushort_t* Wkh   = (ushort_t*)alloc(NN * 2);             //  2.10 MB
    ushort_t* G     = (ushort_t*)alloc(NN * 2);             //  2.10 MB
    ushort_t* WvT   = (ushort_t*)alloc(NN * 2);             //  2.10 MB
    ushort_t* xqh   = (ushort_t*)alloc(8192L * 1024 * 2);   // 16.78 MB
    ushort_t* VTall = (ushort_t*)alloc(1024L * 8192 * 2);   // 16.78 MB
    float* sigma    = (float*)alloc(8192 * 4);
    float* rowsum   = (float*)alloc(8192 * 4);
    float* batchsum = (float*)alloc(64);
    // overlays: scores (f32) -> Pout (dead until svp's filler blocks, which
    //           run after softmax consumed scores); S (bf16) -> xh (x-input
    //           dead after scores gemm)
    float*    scores = Pout;
    ushort_t* Sh     = xh;

    // 1. prep: x->bf16 + sigma + rowsum | Wq/Wk copy | Wv transpose
    prep<<<768, 256, 0, stream>>>(x, Ws, Wq, Wk, Wv, xh, sigma, rowsum,
                                  Wqh, Wkh, WvT);
    // 2. VT = Wv^T x^T | G = Wk Wq^T | batch_reduce
    gvt<<<296, 512, 0, stream>>>(WvT, xh, VTall, Wkh, Wqh, G, rowsum, batchsum);
    // 3. xq = x*(Wq Wk^T)  (by-fastest: XCD chunk = 8 A-tiles + G)
    gemm3b<1><<<256, 512, 0, stream>>>(
        xh, G, xqh, 1024, 1024, 1024, 0, 0, 0, 1.f, 4, 64, 0);
    // 4. scores = xq x^T / 32  (one batch per XCD; f32 -> Pout scratch)
    gemm3b<0><<<256, 512, 0, stream>>>(
        xqh, xh, scores, 1024, 1024, 1024, ND, ND, NN, 0.03125f, 8, 4, 1);
    // 5. softmax over batch -> S (bf16, overlays xh)
    softmax_batch<<<4096, 256, 0, stream>>>(scores, Sh);
    // 6. Z = S V | prior P write
    svp<<<384, 512, 0, stream>>>(Sh, VTall, Zout, sigma, batchsum, Pout);
}

// Round 8
// 145.647 us; speedup vs baseline: 1.2536x; 1.2536x over previous
//
#include <hip/hip_runtime.h>

// AnomalyAttention forward, MI355X gfx950.
// B=8, N=1024, D=1024. Out = [Z (8*1024*1024 f32), P (8*1024*1024 f32)].
// Round 8: 5-dispatch graph, every dispatch <= 256 blocks of its LDS class:
//   prep_g  : x->bf16+sigma+rowsum (192) | WvT (64) | G=Wk*Wq^T f32-in (64)
//   xq      : gemm3b 128x256 (256 blk, verified round-3/6 body)
//   sc_vt   : scores@256^2 (128) | VT@256^2 (128)   (verified round-4 body)
//   softmax : batch softmax (4096x256)
//   sv_prior: Z=S*V@256^2 (128) | prior P write + own batchsum (128)

typedef __attribute__((ext_vector_type(8))) short bf16x8;
typedef __attribute__((ext_vector_type(4))) float f32x4;
typedef unsigned short ushort_t;

#define DI __device__ __forceinline__

constexpr long NN = 1024L * 1024L;
constexpr long ND = 1024L * 1024L;

DI ushort_t f2bf(float f) {  // round-to-nearest-even f32 -> bf16 bits
    unsigned int u = __float_as_uint(f);
    u = u + 0x7fffu + ((u >> 16) & 1u);
    return (ushort_t)(u >> 16);
}

// ---------------------------------------------------------------------------
// 128x256 pipelined GEMM body (byte-identical sync structure to round-3/6):
// 3 LDS buffers, XOR-swizzle, 2 phases/K-tile, prefetch dist 2, vmcnt(6).
// ---------------------------------------------------------------------------
template <int OUT_BF16>
DI void g3b_body(const ushort_t* __restrict__ Ab, const ushort_t* __restrict__ Bb,
                 void* __restrict__ Cb, int ldA, int ldB, int ldC,
                 float scale, int bx, int by, ushort_t* lds)
{
    constexpr int BUF   = 24576;
    constexpr int B_OFF = 8192;

    const int tid  = threadIdx.x;
    const int wave = tid >> 6;
    const int lane = tid & 63;
    const int wm   = wave >> 2;
    const int wn   = wave & 3;
    const int gm   = bx * 128;
    const int gn   = by * 256;

    const int srow = tid >> 3;
    const int scol = 8 * ((tid & 7) ^ (srow & 7));
    const int sdst = wave * 512;

    auto stageA = [&](int t, int d, int h) {
        const ushort_t* src = Ab + (long)(gm + h * 64 + srow) * ldA + t * 64 + scol;
        __builtin_amdgcn_global_load_lds(
            (const __attribute__((address_space(1))) void*)src,
            (__attribute__((address_space(3))) void*)(&lds[d * BUF + h * 4096 + sdst]),
            16, 0, 0);
    };
    auto stageB = [&](int t, int d, int h, int j) {
        const ushort_t* src = Bb + (long)(gn + h * 128 + j * 64 + srow) * ldB + t * 64 + scol;
        __builtin_amdgcn_global_load_lds(
            (const __attribute__((address_space(1))) void*)src,
            (__attribute__((address_space(3))) void*)(&lds[d * BUF + B_OFF + h * 8192 + j * 4096 + sdst]),
            16, 0, 0);
    };

    const int arow = wm * 64 + (lane & 15);
    const int brow = wn * 64 + (lane & 15);
    const int cs0 = (((lane >> 4) * 16) ^ ((lane & 7) << 4)) >> 1;
    const int cs1 = ((64 + (lane >> 4) * 16) ^ ((lane & 7) << 4)) >> 1;

    f32x4 acc[4][4];
#pragma unroll
    for (int m = 0; m < 4; ++m)
#pragma unroll
        for (int n = 0; n < 4; ++n) acc[m][n] = (f32x4){0.f, 0.f, 0.f, 0.f};

    stageA(0, 0, 0); stageA(0, 0, 1);
    stageB(0, 0, 0, 0); stageB(0, 0, 0, 1); stageB(0, 0, 1, 0); stageB(0, 0, 1, 1);
    stageA(1, 1, 0); stageA(1, 1, 1);
    stageB(1, 1, 0, 0); stageB(1, 1, 0, 1); stageB(1, 1, 1, 0); stageB(1, 1, 1, 1);
    asm volatile("s_waitcnt vmcnt(6)" ::: "memory");
    __builtin_amdgcn_s_barrier();
    __builtin_amdgcn_sched_barrier(0);

    int cur = 0;
    for (int t = 0; t < 16; ++t) {
        const int nxt = (cur == 0) ? 2 : cur - 1;
        const ushort_t* la = &lds[cur * BUF];
        const ushort_t* lb = &lds[cur * BUF + B_OFF];

        bf16x8 a[2][4], b[2][4];
#pragma unroll
        for (int mi = 0; mi < 4; ++mi) {
            a[0][mi] = *(const bf16x8*)&la[(arow + mi * 16) * 64 + cs0];
            a[1][mi] = *(const bf16x8*)&la[(arow + mi * 16) * 64 + cs1];
        }
#pragma unroll
        for (int ni = 0; ni < 2; ++ni) {
            b[0][ni] = *(const bf16x8*)&lb[(brow + ni * 16) * 64 + cs0];
            b[1][ni] = *(const bf16x8*)&lb[(brow + ni * 16) * 64 + cs1];
        }
        if (t < 14) {
            stageB(t + 2, nxt, 0, 0); stageB(t + 2, nxt, 0, 1);
            stageB(t + 2, nxt, 1, 0); stageB(t + 2, nxt, 1, 1);
        }
        __builtin_amdgcn_s_barrier();
        asm volatile("s_waitcnt lgkmcnt(0)" ::: "memory");
        __builtin_amdgcn_sched_barrier(0);
        __builtin_amdgcn_s_setprio(1);
#pragma unroll
        for (int mi = 0; mi < 4; ++mi)
#pragma unroll
            for (int ni = 0; ni < 2; ++ni) {
                acc[mi][ni] = __builtin_amdgcn_mfma_f32_16x16x32_bf16(a[0][mi], b[0][ni], acc[mi][ni], 0, 0, 0);
                acc[mi][ni] = __builtin_amdgcn_mfma_f32_16x16x32_bf16(a[1][mi], b[1][ni], acc[mi][ni], 0, 0, 0);
            }
        __builtin_amdgcn_s_setprio(0);
        __builtin_amdgcn_s_barrier();
        __builtin_amdgcn_sched_barrier(0);

#pragma unroll
        for (int ni = 2; ni < 4; ++ni) {
            b[0][ni] = *(const bf16x8*)&lb[(brow + ni * 16) * 64 + cs0];
            b[1][ni] = *(const bf16x8*)&lb[(brow + ni * 16) * 64 + cs1];
        }
        if (t < 14) { stageA(t + 2, nxt, 0); stageA(t + 2, nxt, 1); }
        __builtin_amdgcn_s_barrier();
        asm volatile("s_waitcnt lgkmcnt(0)" ::: "memory");
        if (t < 14) asm volatile("s_waitcnt vmcnt(6)" ::: "memory");
        else        asm volatile("s_waitcnt vmcnt(0)" ::: "memory");
        __builtin_amdgcn_sched_barrier(0);
        __builtin_amdgcn_s_setprio(1);
#pragma unroll
        for (int mi = 0; mi < 4; ++mi)
#pragma unroll
            for (int ni = 2; ni < 4; ++ni) {
                acc[mi][ni] = __builtin_amdgcn_mfma_f32_16x16x32_bf16(a[0][mi], b[0][ni], acc[mi][ni], 0, 0, 0);
                acc[mi][ni] = __builtin_amdgcn_mfma_f32_16x16x32_bf16(a[1][mi], b[1][ni], acc[mi][ni], 0, 0, 0);
            }
        __builtin_amdgcn_s_setprio(0);
        __builtin_amdgcn_s_barrier();
        __builtin_amdgcn_sched_barrier(0);

        cur = (cur == 2) ? 0 : cur + 1;
    }

    if (OUT_BF16) {
        ushort_t* el = lds;
#pragma unroll
        for (int mi = 0; mi < 4; ++mi)
#pragma unroll
            for (int ni = 0; ni < 4; ++ni)
#pragma unroll
                for (int r = 0; r < 4; ++r)
                    el[(wm * 64 + mi * 16 + (lane >> 4) * 4 + r) * 256 +
                       wn * 64 + ni * 16 + (lane & 15)] = f2bf(acc[mi][ni][r] * scale);
        __builtin_amdgcn_s_barrier();
        ushort_t* C = (ushort_t*)Cb;
#pragma unroll
        for (int rr = 0; rr < 8; ++rr) {
            const int row = rr * 16 + (tid >> 5);
            const int col = (tid & 31) * 8;
            *(bf16x8*)&C[(long)(gm + row) * ldC + gn + col] =
                *(const bf16x8*)&el[row * 256 + col];
        }
    } else {
        float* el = (float*)lds;
        float* C  = (float*)Cb;
#pragma unroll
        for (int h = 0; h < 2; ++h) {
            if (wm == h) {
#pragma unroll
                for (int mi = 0; mi < 4; ++mi)
#pragma unroll
                    for (int ni = 0; ni < 4; ++ni)
#pragma unroll
                        for (int r = 0; r < 4; ++r)
                            el[(mi * 16 + (lane >> 4) * 4 + r) * 256 +
                               wn * 64 + ni * 16 + (lane & 15)] = acc[mi][ni][r] * scale;
            }
            __builtin_amdgcn_s_barrier();
#pragma unroll
            for (int i = 0; i < 8; ++i) {
                const int cc  = i * 512 + tid;
                const int row = cc >> 6;
                const int c4  = (cc & 63) * 4;
                *(float4*)&C[(long)(gm + h * 64 + row) * ldC + gn + c4] =
                    *(const float4*)&el[row * 256 + c4];
            }
            __builtin_amdgcn_s_barrier();
        }
    }
}

template <int OUT_BF16>
__global__ __launch_bounds__(512, 2)
void gemm3b(const ushort_t* __restrict__ A, const ushort_t* __restrict__ B,
            void* __restrict__ Cout, int ldA, int ldB, int ldC,
            long sA, long sB, long sC, float scale,
            int n0, int n1, int xfirst)
{
    __shared__ ushort_t lds[3 * 24576];
    const int total = gridDim.x;
    const int lin   = blockIdx.x;
    const int swz   = (lin & 7) * (total >> 3) + (lin >> 3);
    const int c0    = swz % n0;
    const int rem   = swz / n0;
    const int c1    = rem % n1;
    const int bz    = rem / n1;
    const int bx    = xfirst ? c0 : c1;
    const int by    = xfirst ? c1 : c0;
    void* Cb = OUT_BF16 ? (void*)((ushort_t*)Cout + (long)bz * sC)
                        : (void*)((float*)Cout + (long)bz * sC);
    g3b_body<OUT_BF16>(A + (long)bz * sA, B + (long)bz * sB, Cb,
                       ldA, ldB, ldC, scale, bx, by, lds);
}

// ---------------------------------------------------------------------------
// 256x256 8-phase GEMM body (byte-identical sync structure to round-4):
// BK=64, 8 waves 2Mx4N, per-wave 128x64, 2 LDS bufs, counted vmcnt(8).
// ---------------------------------------------------------------------------
template <int OUT_BF16>
DI void g256_body(const ushort_t* __restrict__ Ab, const ushort_t* __restrict__ Bb,
                  void* __restrict__ Cb, int ldA, int ldB, int ldC,
                  float scale, int bx, int by, ushort_t* ldsp)
{
    constexpr int BUF   = 32768;
    constexpr int B_OFF = 16384;

    const int tid  = threadIdx.x;
    const int wave = tid >> 6;
    const int lane = tid & 63;
    const int wm   = wave >> 2;
    const int wn   = wave & 3;
    const int gm   = bx * 256;
    const int gn   = by * 256;

    const int srow = tid >> 3;
    const int scol = 8 * ((tid & 7) ^ (srow & 7));
    const int sdst = wave * 512;

    auto stage = [&](int t, int d, int op, int h) {
        const ushort_t* g  = op ? Bb : Ab;
        const int       ld = op ? ldB : ldA;
        const int       g0 = (op ? gn : gm) + h * 128;
#pragma unroll
        for (int j = 0; j < 2; ++j) {
            const ushort_t* src = g + (long)(g0 + j * 64 + srow) * ld + t * 64 + scol;
            __builtin_amdgcn_global_load_lds(
                (const __attribute__((address_space(1))) void*)src,
                (__attribute__((address_space(3))) void*)
                    (&ldsp[d * BUF + op * B_OFF + h * 8192 + j * 4096 + sdst]),
                16, 0, 0);
        }
    };

    const int arow = wm * 128 + (lane & 15);
    const int brow = wn * 64 + (lane & 15);
    const int cs0 = (((lane >> 4) * 16) ^ ((lane & 7) << 4)) >> 1;
    const int cs1 = ((64 + (lane >> 4) * 16) ^ ((lane & 7) << 4)) >> 1;

    f32x4 acc[8][4];
#pragma unroll
    for (int m = 0; m < 8; ++m)
#pragma unroll
        for (int n = 0; n < 4; ++n) acc[m][n] = (f32x4){0.f, 0.f, 0.f, 0.f};

    stage(0, 0, 0, 0); stage(0, 0, 0, 1); stage(0, 0, 1, 0); stage(0, 0, 1, 1);
    stage(1, 1, 0, 0); stage(1, 1, 0, 1); stage(1, 1, 1, 0); stage(1, 1, 1, 1);
    asm volatile("s_waitcnt vmcnt(8)" ::: "memory");
    __builtin_amdgcn_s_barrier();
    __builtin_amdgcn_sched_barrier(0);

    bf16x8 a[2][4], b0[2][2], b1[2][2];
#pragma unroll 2
    for (int t = 0; t < 16; ++t) {
        const int cur = t & 1;
        const ushort_t* la = &ldsp[cur * BUF];
        const ushort_t* lb = &ldsp[cur * BUF + B_OFF];

        // ph1
#pragma unroll
        for (int mi = 0; mi < 4; ++mi) {
            a[0][mi] = *(const bf16x8*)&la[(arow + mi * 16) * 64 + cs0];
            a[1][mi] = *(const bf16x8*)&la[(arow + mi * 16) * 64 + cs1];
        }
#pragma unroll
        for (int ni = 0; ni < 2; ++ni) {
            b0[0][ni] = *(const bf16x8*)&lb[(brow + ni * 16) * 64 + cs0];
            b0[1][ni] = *(const bf16x8*)&lb[(brow + ni * 16) * 64 + cs1];
        }
        __builtin_amdgcn_s_barrier();
        asm volatile("s_waitcnt lgkmcnt(0)" ::: "memory");
        __builtin_amdgcn_sched_barrier(0);
        __builtin_amdgcn_s_setprio(1);
#pragma unroll
        for (int mi = 0; mi < 4; ++mi)
#pragma unroll
            for (int ni = 0; ni < 2; ++ni) {
                acc[mi][ni] = __builtin_amdgcn_mfma_f32_16x16x32_bf16(a[0][mi], b0[0][ni], acc[mi][ni], 0, 0, 0);
                acc[mi][ni] = __builtin_amdgcn_mfma_f32_16x16x32_bf16(a[1][mi], b0[1][ni], acc[mi][ni], 0, 0, 0);
            }
        __builtin_amdgcn_s_setprio(0);
        __builtin_amdgcn_s_barrier();
        __builtin_amdgcn_sched_barrier(0);

        // ph2
#pragma unroll
        for (int ni = 0; ni < 2; ++ni) {
            b1[0][ni] = *(const bf16x8*)&lb[(brow + (ni + 2) * 16) * 64 + cs0];
            b1[1][ni] = *(const bf16x8*)&lb[(brow + (ni + 2) * 16) * 64 + cs1];
        }
        __builtin_amdgcn_s_barrier();
        asm volatile("s_waitcnt lgkmcnt(0)" ::: "memory");
        __builtin_amdgcn_sched_barrier(0);
        __builtin_amdgcn_s_setprio(1);
#pragma unroll
        for (int mi = 0; mi < 4; ++mi)
#pragma unroll
            for (int ni = 0; ni < 2; ++ni) {
                acc[mi][ni + 2] = __builtin_amdgcn_mfma_f32_16x16x32_bf16(a[0][mi], b1[0][ni], acc[mi][ni + 2], 0, 0, 0);
                acc[mi][ni + 2] = __builtin_amdgcn_mfma_f32_16x16x32_bf16(a[1][mi], b1[1][ni], acc[mi][ni + 2], 0, 0, 0);
            }
        __builtin_amdgcn_s_setprio(0);
        __builtin_amdgcn_s_barrier();
        __builtin_amdgcn_sched_barrier(0);

        // ph3
#pragma unroll
        for (int mi = 0; mi < 4; ++mi) {
            a[0][mi] = *(const bf16x8*)&la[(arow + (mi + 4) * 16) * 64 + cs0];
            a[1][mi] = *(const bf16x8*)&la[(arow + (mi + 4) * 16) * 64 + cs1];
        }
        if (t < 14) { stage(t + 2, cur, 1, 0); stage(t + 2, cur, 1, 1); }
        __builtin_amdgcn_s_barrier();
        asm volatile("s_waitcnt lgkmcnt(0)" ::: "memory");
        __builtin_amdgcn_sched_barrier(0);
        __builtin_amdgcn_s_setprio(1);
#pragma unroll
        for (int mi = 0; mi < 4; ++mi)
#pragma unroll
            for (int ni = 0; ni < 2; ++ni) {
                acc[mi + 4][ni + 2] = __builtin_amdgcn_mfma_f32_16x16x32_bf16(a[0][mi], b1[0][ni], acc[mi + 4][ni + 2], 0, 0, 0);
                acc[mi + 4][ni + 2] = __builtin_amdgcn_mfma_f32_16x16x32_bf16(a[1][mi], b1[1][ni], acc[mi + 4][ni + 2], 0, 0, 0);
            }
        __builtin_amdgcn_s_setprio(0);
        __builtin_amdgcn_s_barrier();
        __builtin_amdgcn_sched_barrier(0);

        // ph4
        if (t < 14) { stage(t + 2, cur, 0, 0); stage(t + 2, cur, 0, 1); }
        if (t < 14)       asm volatile("s_waitcnt vmcnt(8)" ::: "memory");
        else if (t == 14) asm volatile("s_waitcnt vmcnt(0)" ::: "memory");
        __builtin_amdgcn_sched_barrier(0);
        __builtin_amdgcn_s_setprio(1);
#pragma unroll
        for (int mi = 0; mi < 4; ++mi)
#pragma unroll
            for (int ni = 0; ni < 2; ++ni) {
                acc[mi + 4][ni] = __builtin_amdgcn_mfma_f32_16x16x32_bf16(a[0][mi], b0[0][ni], acc[mi + 4][ni], 0, 0, 0);
                acc[mi + 4][ni] = __builtin_amdgcn_mfma_f32_16x16x32_bf16(a[1][mi], b0[1][ni], acc[mi + 4][ni], 0, 0, 0);
            }
        __builtin_amdgcn_s_setprio(0);
        __builtin_amdgcn_s_barrier();
        __builtin_amdgcn_sched_barrier(0);
    }

    if (OUT_BF16) {
        ushort_t* el = ldsp;
#pragma unroll
        for (int mi = 0; mi < 8; ++mi)
#pragma unroll
            for (int ni = 0; ni < 4; ++ni)
#pragma unroll
                for (int r = 0; r < 4; ++r)
                    el[(wm * 128 + mi * 16 + (lane >> 4) * 4 + r) * 256 +
                       wn * 64 + ni * 16 + (lane & 15)] = f2bf(acc[mi][ni][r] * scale);
        __builtin_amdgcn_s_barrier();
        ushort_t* C = (ushort_t*)Cb;
#pragma unroll
        for (int i = 0; i < 16; ++i) {
            const int cc  = i * 512 + tid;
            const int row = cc >> 5;
            const int col = (cc & 31) * 8;
            *(bf16x8*)&C[(long)(gm + row) * ldC + gn + col] =
                *(const bf16x8*)&el[row * 256 + col];
        }
    } else {
        float* el = (float*)ldsp;
        float* C  = (float*)Cb;
#pragma unroll
        for (int h = 0; h < 2; ++h) {
            if (wm == h) {
#pragma unroll
                for (int mi = 0; mi < 8; ++mi)
#pragma unroll
                    for (int ni = 0; ni < 4; ++ni)
#pragma unroll
                        for (int r = 0; r < 4; ++r)
                            el[(mi * 16 + (lane >> 4) * 4 + r) * 256 +
                               wn * 64 + ni * 16 + (lane & 15)] = acc[mi][ni][r] * scale;
            }
            __builtin_amdgcn_s_barrier();
#pragma unroll
            for (int i = 0; i < 16; ++i) {
                const int cc  = i * 512 + tid;
                const int row = cc >> 6;
                const int c4  = (cc & 63) * 4;
                *(float4*)&C[(long)(gm + h * 128 + row) * ldC + gn + c4] =
                    *(const float4*)&el[row * 256 + c4];
            }
            __builtin_amdgcn_s_barrier();
        }
    }
}

// ---------------------------------------------------------------------------
// prep_g: 320 blocks x 512 thr, ~20.5 KB LDS (multi-resident).
//   blocks 0..191:  x -> bf16 + sigma + prior rowsum (wave per row, strided)
//   blocks 192..255: WvT transpose, 4 64x64 tiles each
//   blocks 256..319: G = Wk * Wq^T, f32 inputs, reg-staged cvt, 128^2 tile
// ---------------------------------------------------------------------------
__global__ __launch_bounds__(512)
void prep_g(const float* __restrict__ x, const float* __restrict__ Ws,
            const float* __restrict__ Wq, const float* __restrict__ Wk,
            const float* __restrict__ Wv,
            ushort_t* __restrict__ xh, float* __restrict__ sigma,
            float* __restrict__ rowsum,
            ushort_t* __restrict__ WvT, ushort_t* __restrict__ G)
{
    __shared__ char smem[20480];
    const int blk = blockIdx.x;
    const int tid = threadIdx.x;

    if (blk < 192) {
        const int wave = tid >> 6, lane = tid & 63;
        for (int row = blk * 8 + wave; row < 8192; row += 1536) {
            const float* xr = x + (long)row * 1024;
            float dot = 0.f;
#pragma unroll
            for (int c = 0; c < 4; ++c) {
                const int i = c * 256 + lane * 4;
                float4 v = *(const float4*)(xr + i);
                float4 w = *(const float4*)(Ws + i);
                dot += v.x * w.x + v.y * w.y + v.z * w.z + v.w * w.w;
                ushort4 o;
                o.x = f2bf(v.x); o.y = f2bf(v.y); o.z = f2bf(v.z); o.w = f2bf(v.w);
                *(ushort4*)(xh + (long)row * 1024 + i) = o;
            }
#pragma unroll
            for (int o = 32; o; o >>= 1) dot += __shfl_down(dot, o);
            float sg;
            if (lane == 0) {
                float s = 1.f / (1.f + __expf(-5.f * dot)) + 1e-5f;
                sg = exp2f(s * 1.5849625007211562f) - 1.f;   // 3^s - 1
            }
            sg = __shfl(sg, 0);
            const int i = row & 1023;
            const float c = -0.5f / (sg * sg);
            float a = 0.f;
            for (int j = lane; j < 1024; j += 64) {
                float d = (float)(i - j);
                a += __expf(c * d * d);
            }
#pragma unroll
            for (int o = 32; o; o >>= 1) a += __shfl_down(a, o);
            if (lane == 0) {
                sigma[row]  = sg;
                rowsum[row] = (0.3989422804014327f / sg) * a;
            }
        }
    } else if (blk < 256) {
        float (*s)[65] = (float(*)[65])smem;
        const int r = tid >> 4, c4 = (tid & 15) * 4;   // r: 0..31
#pragma unroll
        for (int it = 0; it < 4; ++it) {
            const int tile = (blk - 192) * 4 + it;
            const int tr = (tile >> 4) * 64, tc = (tile & 15) * 64;
#pragma unroll
            for (int rr = r; rr < 64; rr += 32) {
                float4 v = *(const float4*)(Wv + (long)(tr + rr) * 1024 + tc + c4);
                s[rr][c4] = v.x; s[rr][c4 + 1] = v.y; s[rr][c4 + 2] = v.z; s[rr][c4 + 3] = v.w;
            }
            __syncthreads();
#pragma unroll
            for (int rr = r; rr < 64; rr += 32) {
                ushort4 o;
                o.x = f2bf(s[c4][rr]);     o.y = f2bf(s[c4 + 1][rr]);
                o.z = f2bf(s[c4 + 2][rr]); o.w = f2bf(s[c4 + 3][rr]);
                *(ushort4*)(WvT + (long)(tc + rr) * 1024 + tr + c4) = o;
            }
            __syncthreads();
        }
    } else {
        // G = Wk * Wq^T (bf16 out): A = Wk rows (M), Bt = Wq rows (N), K=1024.
        // 128x128 tile, 8 waves (2M x 4N), per-wave 64x32 = acc[4][2].
        // LDS [128][40] ushort per operand (pad 40: 16B-aligned rows, 2-way bank).
        ushort_t* sA = (ushort_t*)smem;          // 128*40 = 5120 ushorts
        ushort_t* sB = sA + 5120;
        const int g  = blk - 256;                // 0..63
        const int gm = (g >> 3) * 128, gn = (g & 7) * 128;
        const int wave = tid >> 6, lane = tid & 63;
        const int wm = wave >> 2, wn = wave & 3;
        const int lrow = tid >> 3, lcol = (tid & 7) * 4;   // 64 rows/pass

        f32x4 acc[4][2];
#pragma unroll
        for (int m = 0; m < 4; ++m)
#pragma unroll
            for (int n = 0; n < 2; ++n) acc[m][n] = (f32x4){0.f, 0.f, 0.f, 0.f};

        for (int k0 = 0; k0 < 1024; k0 += 32) {
#pragma unroll
            for (int p = 0; p < 2; ++p) {
                const int row = p * 64 + lrow;
                float4 va = *(const float4*)(Wk + (long)(gm + row) * 1024 + k0 + lcol);
                float4 vb = *(const float4*)(Wq + (long)(gn + row) * 1024 + k0 + lcol);
                ushort4 oa, ob;
                oa.x = f2bf(va.x); oa.y = f2bf(va.y); oa.z = f2bf(va.z); oa.w = f2bf(va.w);
                ob.x = f2bf(vb.x); ob.y = f2bf(vb.y); ob.z = f2bf(vb.z); ob.w = f2bf(vb.w);
                *(ushort4*)&sA[row * 40 + lcol] = oa;
                *(ushort4*)&sB[row * 40 + lcol] = ob;
            }
            __syncthreads();
            bf16x8 af[4], bfv[2];
#pragma unroll
            for (int mi = 0; mi < 4; ++mi)
                af[mi] = *(const bf16x8*)&sA[(wm * 64 + mi * 16 + (lane & 15)) * 40 + (lane >> 4) * 8];
#pragma unroll
            for (int ni = 0; ni < 2; ++ni)
                bfv[ni] = *(const bf16x8*)&sB[(wn * 32 + ni * 16 + (lane & 15)) * 40 + (lane >> 4) * 8];
#pragma unroll
            for (int mi = 0; mi < 4; ++mi)
#pragma unroll
                for (int ni = 0; ni < 2; ++ni)
                    acc[mi][ni] = __builtin_amdgcn_mfma_f32_16x16x32_bf16(af[mi], bfv[ni], acc[mi][ni], 0, 0, 0);
            __syncthreads();
        }
        // C/D layout: col = lane&15, row = (lane>>4)*4 + r
#pragma unroll
        for (int mi = 0; mi < 4; ++mi)
#pragma unroll
            for (int ni = 0; ni < 2; ++ni)
#pragma unroll
                for (int r = 0; r < 4; ++r)
                    G[(long)(gm + wm * 64 + mi * 16 + (lane >> 4) * 4 + r) * 1024 +
                      gn + wn * 32 + ni * 16 + (lane & 15)] = f2bf(acc[mi][ni][r]);
    }
}

// ---------------------------------------------------------------------------
// sc_vt: 256 blocks x 512 thr, 128 KB LDS (one residency round).
//   lin 0..127:   scores_b = xq_b * x_b^T / 32  (f32 -> Pout scratch), b = lin&7
//   lin 128..255: VT = Wv^T x^T (bf16, ld 8192)
// ---------------------------------------------------------------------------
__global__ __launch_bounds__(512, 2)
void sc_vt(const ushort_t* __restrict__ xqh, const ushort_t* __restrict__ xh,
           float* __restrict__ scores,
           const ushort_t* __restrict__ WvT, ushort_t* __restrict__ VTall)
{
    __shared__ ushort_t lds[2 * 32768];
    const int lin = blockIdx.x;
    if (lin < 128) {
        const int bz = lin & 7;
        const int t  = lin >> 3;           // 0..15
        g256_body<0>(xqh + (long)bz * ND, xh + (long)bz * ND,
                     (void*)(scores + (long)bz * NN),
                     1024, 1024, 1024, 0.03125f, t & 3, t >> 2, lds);
    } else {
        const int l  = lin - 128;
        const int l2 = (l & 7) * 16 + (l >> 3);   // chunked per XCD
        g256_body<1>(WvT, xh, (void*)VTall,
                     1024, 1024, 8192, 1.f, l2 & 3, l2 >> 2, lds);
    }
}

// ---------------------------------------------------------------------------
// sv_prior: 256 blocks x 512 thr, 128 KB LDS (one residency round).
//   lin 0..127:   Z_b = S_b * V_b (f32), b = lin&7
//   lin 128..255: prior P write; each block derives batchsum from rowsum
// ---------------------------------------------------------------------------
__global__ __launch_bounds__(512, 2)
void sv_prior(const ushort_t* __restrict__ S, const ushort_t* __restrict__ VTall,
              float* __restrict__ Z, const float* __restrict__ sigma,
              const float* __restrict__ rowsum, float* __restrict__ P)
{
    __shared__ ushort_t lds[2 * 32768];
    const int lin = blockIdx.x;
    const int tid = threadIdx.x;
    if (lin < 128) {
        const int bz = lin & 7;
        const int t  = lin >> 3;
        g256_body<0>(S + (long)bz * NN, VTall + bz * 1024,
                     (void*)(Z + (long)bz * ND),
                     1024, 8192, 1024, 1.f, t & 3, t >> 2, lds);
    } else {
        const int l = lin - 128;           // 0..127
        const int b = l >> 4;              // 16 blocks per batch
        float* sred = (float*)lds;
        float a = rowsum[b * 1024 + tid] + rowsum[b * 1024 + 512 + tid];
        sred[tid] = a; __syncthreads();
        for (int o = 256; o; o >>= 1) { if (tid < o) sred[tid] += sred[tid + o]; __syncthreads(); }
        const float bs = sred[0];
        const int r0 = (l & 15) * 64;      // 64 rows per block
#pragma unroll
        for (int it = 0; it < 32; ++it) {
            const int e   = it * 512 + tid;        // 0..16383
            const int row = r0 + (e >> 8);
            const int j4  = (e & 255) * 4;
            const float sg  = sigma[(b << 10) + row];
            const float c   = -0.5f / (sg * sg);
            const float inv = 0.3989422804014327f / (sg * bs);
            float4 o;
            float d;
            d = (float)(row - j4);       o.x = inv * __expf(c * d * d);
            d = (float)(row - j4 - 1);   o.y = inv * __expf(c * d * d);
            d = (float)(row - j4 - 2);   o.z = inv * __expf(c * d * d);
            d = (float)(row - j4 - 3);   o.w = inv * __expf(c * d * d);
            *(float4*)&P[(long)b * NN + (long)row * 1024 + j4] = o;
        }
    }
}

// softmax over batch dim (8 values, stride NN)
__global__ void softmax_batch(const float* __restrict__ scores, ushort_t* __restrict__ S)
{
    const long idx = (long)blockIdx.x * 256 + threadIdx.x;
    float v[8], m = -1e30f;
#pragma unroll
    for (int b = 0; b < 8; ++b) { v[b] = scores[(long)b * NN + idx]; m = fmaxf(m, v[b]); }
    float sum = 0.f;
#pragma unroll
    for (int b = 0; b < 8; ++b) { v[b] = __expf(v[b] - m); sum += v[b]; }
    const float inv = 1.f / sum;
#pragma unroll
    for (int b = 0; b < 8; ++b) S[(long)b * NN + idx] = f2bf(v[b] * inv);
}

// ---------------------------------------------------------------------------
extern "C" void kernel_launch(void* const* d_in, const int* in_sizes, int n_in,
                              void* d_out, int out_size, void* d_ws, size_t ws_size,
                              hipStream_t stream)
{
    const float* x  = (const float*)d_in[0];
    const float* Wq = (const float*)d_in[1];
    const float* Wk = (const float*)d_in[2];
    const float* Wv = (const float*)d_in[3];
    const float* Ws = (const float*)d_in[4];
    float* Zout = (float*)d_out;
    float* Pout = Zout + 8 * ND;

    char* base = (char*)d_ws;
    size_t off = 0;
    auto alloc = [&](size_t bytes) {
        void* p = base + off;
        off = (off + bytes + 255) & ~(size_t)255;
        return p;
    };
    ushort_t* xh    = (ushort_t*)alloc(8192L * 1024 * 2);   // 16.78 MB
    ushort_t* G     = (ushort_t*)alloc(NN * 2);             //  2.10 MB
    ushort_t* WvT   = (ushort_t*)alloc(NN * 2);             //  2.10 MB
    ushort_t* xqh   = (ushort_t*)alloc(8192L * 1024 * 2);   // 16.78 MB
    ushort_t* VTall = (ushort_t*)alloc(1024L * 8192 * 2);   // 16.78 MB
    float* sigma    = (float*)alloc(8192 * 4);
    float* rowsum   = (float*)alloc(8192 * 4);
    // overlays: scores (f32) -> Pout (consumed by softmax before sv_prior's
    //           prior blocks overwrite it); S (bf16) -> xh (x-input dead
    //           after sc_vt)
    float*    scores = Pout;
    ushort_t* Sh     = xh;

    // 1. prep (x->bf16+sigma+rowsum | WvT) + G = Wk*Wq^T (f32-direct)
    prep_g<<<320, 512, 0, stream>>>(x, Ws, Wq, Wk, Wv, xh, sigma, rowsum, WvT, G);
    // 2. xq = x * (Wq Wk^T)   (256 blocks, by-fastest XCD chunking)
    gemm3b<1><<<256, 512, 0, stream>>>(
        xh, G, xqh, 1024, 1024, 1024, 0, 0, 0, 1.f, 4, 64, 0);
    // 3. scores (128 @256^2, batch=XCD) | VT (128 @256^2, chunked)
    sc_vt<<<256, 512, 0, stream>>>(xqh, xh, scores, WvT, VTall);
    // 4. softmax over batch -> S (bf16, overlays xh)
    softmax_batch<<<4096, 256, 0, stream>>>(scores, Sh);
    // 5. Z = S V (128 @256^2, batch=XCD) | prior P write (128, own batchsum)
    sv_prior<<<256, 512, 0, stream>>>(Sh, VTall, Zout, sigma, rowsum, Pout);
}

// Round 9
// 133.005 us; speedup vs baseline: 1.3727x; 1.0950x over previous
//
#include <hip/hip_runtime.h>

// AnomalyAttention forward, MI355X gfx950.
// B=8, N=1024, D=1024. Out = [Z (8*1024*1024 f32), P (8*1024*1024 f32)].
// Round 9: prep_g fixed — 256 blocks (1/CU), G role software-pipelined
// (2-deep register prefetch). Rest identical to round 8 (145.6 us):
//   prep_g  : x-prep (160) | WvT (32) | G=Wk*Wq^T pipelined (64)
//   xq      : gemm3b 128x256 (256 blk)
//   sc_vt   : scores@256^2 (128) | VT@256^2 (128)
//   softmax : batch softmax
//   sv_prior: Z=S*V@256^2 (128) | prior P write (128)

typedef __attribute__((ext_vector_type(8))) short bf16x8;
typedef __attribute__((ext_vector_type(4))) float f32x4;
typedef unsigned short ushort_t;

#define DI __device__ __forceinline__

constexpr long NN = 1024L * 1024L;
constexpr long ND = 1024L * 1024L;

DI ushort_t f2bf(float f) {  // round-to-nearest-even f32 -> bf16 bits
    unsigned int u = __float_as_uint(f);
    u = u + 0x7fffu + ((u >> 16) & 1u);
    return (ushort_t)(u >> 16);
}

// ---------------------------------------------------------------------------
// 128x256 pipelined GEMM body (verified round-3/6): 3 LDS buffers, XOR
// swizzle, 2 phases/K-tile, prefetch distance 2, vmcnt(6).
// ---------------------------------------------------------------------------
template <int OUT_BF16>
DI void g3b_body(const ushort_t* __restrict__ Ab, const ushort_t* __restrict__ Bb,
                 void* __restrict__ Cb, int ldA, int ldB, int ldC,
                 float scale, int bx, int by, ushort_t* lds)
{
    constexpr int BUF   = 24576;
    constexpr int B_OFF = 8192;

    const int tid  = threadIdx.x;
    const int wave = tid >> 6;
    const int lane = tid & 63;
    const int wm   = wave >> 2;
    const int wn   = wave & 3;
    const int gm   = bx * 128;
    const int gn   = by * 256;

    const int srow = tid >> 3;
    const int scol = 8 * ((tid & 7) ^ (srow & 7));
    const int sdst = wave * 512;

    auto stageA = [&](int t, int d, int h) {
        const ushort_t* src = Ab + (long)(gm + h * 64 + srow) * ldA + t * 64 + scol;
        __builtin_amdgcn_global_load_lds(
            (const __attribute__((address_space(1))) void*)src,
            (__attribute__((address_space(3))) void*)(&lds[d * BUF + h * 4096 + sdst]),
            16, 0, 0);
    };
    auto stageB = [&](int t, int d, int h, int j) {
        const ushort_t* src = Bb + (long)(gn + h * 128 + j * 64 + srow) * ldB + t * 64 + scol;
        __builtin_amdgcn_global_load_lds(
            (const __attribute__((address_space(1))) void*)src,
            (__attribute__((address_space(3))) void*)(&lds[d * BUF + B_OFF + h * 8192 + j * 4096 + sdst]),
            16, 0, 0);
    };

    const int arow = wm * 64 + (lane & 15);
    const int brow = wn * 64 + (lane & 15);
    const int cs0 = (((lane >> 4) * 16) ^ ((lane & 7) << 4)) >> 1;
    const int cs1 = ((64 + (lane >> 4) * 16) ^ ((lane & 7) << 4)) >> 1;

    f32x4 acc[4][4];
#pragma unroll
    for (int m = 0; m < 4; ++m)
#pragma unroll
        for (int n = 0; n < 4; ++n) acc[m][n] = (f32x4){0.f, 0.f, 0.f, 0.f};

    stageA(0, 0, 0); stageA(0, 0, 1);
    stageB(0, 0, 0, 0); stageB(0, 0, 0, 1); stageB(0, 0, 1, 0); stageB(0, 0, 1, 1);
    stageA(1, 1, 0); stageA(1, 1, 1);
    stageB(1, 1, 0, 0); stageB(1, 1, 0, 1); stageB(1, 1, 1, 0); stageB(1, 1, 1, 1);
    asm volatile("s_waitcnt vmcnt(6)" ::: "memory");
    __builtin_amdgcn_s_barrier();
    __builtin_amdgcn_sched_barrier(0);

    int cur = 0;
    for (int t = 0; t < 16; ++t) {
        const int nxt = (cur == 0) ? 2 : cur - 1;
        const ushort_t* la = &lds[cur * BUF];
        const ushort_t* lb = &lds[cur * BUF + B_OFF];

        bf16x8 a[2][4], b[2][4];
#pragma unroll
        for (int mi = 0; mi < 4; ++mi) {
            a[0][mi] = *(const bf16x8*)&la[(arow + mi * 16) * 64 + cs0];
            a[1][mi] = *(const bf16x8*)&la[(arow + mi * 16) * 64 + cs1];
        }
#pragma unroll
        for (int ni = 0; ni < 2; ++ni) {
            b[0][ni] = *(const bf16x8*)&lb[(brow + ni * 16) * 64 + cs0];
            b[1][ni] = *(const bf16x8*)&lb[(brow + ni * 16) * 64 + cs1];
        }
        if (t < 14) {
            stageB(t + 2, nxt, 0, 0); stageB(t + 2, nxt, 0, 1);
            stageB(t + 2, nxt, 1, 0); stageB(t + 2, nxt, 1, 1);
        }
        __builtin_amdgcn_s_barrier();
        asm volatile("s_waitcnt lgkmcnt(0)" ::: "memory");
        __builtin_amdgcn_sched_barrier(0);
        __builtin_amdgcn_s_setprio(1);
#pragma unroll
        for (int mi = 0; mi < 4; ++mi)
#pragma unroll
            for (int ni = 0; ni < 2; ++ni) {
                acc[mi][ni] = __builtin_amdgcn_mfma_f32_16x16x32_bf16(a[0][mi], b[0][ni], acc[mi][ni], 0, 0, 0);
                acc[mi][ni] = __builtin_amdgcn_mfma_f32_16x16x32_bf16(a[1][mi], b[1][ni], acc[mi][ni], 0, 0, 0);
            }
        __builtin_amdgcn_s_setprio(0);
        __builtin_amdgcn_s_barrier();
        __builtin_amdgcn_sched_barrier(0);

#pragma unroll
        for (int ni = 2; ni < 4; ++ni) {
            b[0][ni] = *(const bf16x8*)&lb[(brow + ni * 16) * 64 + cs0];
            b[1][ni] = *(const bf16x8*)&lb[(brow + ni * 16) * 64 + cs1];
        }
        if (t < 14) { stageA(t + 2, nxt, 0); stageA(t + 2, nxt, 1); }
        __builtin_amdgcn_s_barrier();
        asm volatile("s_waitcnt lgkmcnt(0)" ::: "memory");
        if (t < 14) asm volatile("s_waitcnt vmcnt(6)" ::: "memory");
        else        asm volatile("s_waitcnt vmcnt(0)" ::: "memory");
        __builtin_amdgcn_sched_barrier(0);
        __builtin_amdgcn_s_setprio(1);
#pragma unroll
        for (int mi = 0; mi < 4; ++mi)
#pragma unroll
            for (int ni = 2; ni < 4; ++ni) {
                acc[mi][ni] = __builtin_amdgcn_mfma_f32_16x16x32_bf16(a[0][mi], b[0][ni], acc[mi][ni], 0, 0, 0);
                acc[mi][ni] = __builtin_amdgcn_mfma_f32_16x16x32_bf16(a[1][mi], b[1][ni], acc[mi][ni], 0, 0, 0);
            }
        __builtin_amdgcn_s_setprio(0);
        __builtin_amdgcn_s_barrier();
        __builtin_amdgcn_sched_barrier(0);

        cur = (cur == 2) ? 0 : cur + 1;
    }

    if (OUT_BF16) {
        ushort_t* el = lds;
#pragma unroll
        for (int mi = 0; mi < 4; ++mi)
#pragma unroll
            for (int ni = 0; ni < 4; ++ni)
#pragma unroll
                for (int r = 0; r < 4; ++r)
                    el[(wm * 64 + mi * 16 + (lane >> 4) * 4 + r) * 256 +
                       wn * 64 + ni * 16 + (lane & 15)] = f2bf(acc[mi][ni][r] * scale);
        __builtin_amdgcn_s_barrier();
        ushort_t* C = (ushort_t*)Cb;
#pragma unroll
        for (int rr = 0; rr < 8; ++rr) {
            const int row = rr * 16 + (tid >> 5);
            const int col = (tid & 31) * 8;
            *(bf16x8*)&C[(long)(gm + row) * ldC + gn + col] =
                *(const bf16x8*)&el[row * 256 + col];
        }
    } else {
        float* el = (float*)lds;
        float* C  = (float*)Cb;
#pragma unroll
        for (int h = 0; h < 2; ++h) {
            if (wm == h) {
#pragma unroll
                for (int mi = 0; mi < 4; ++mi)
#pragma unroll
                    for (int ni = 0; ni < 4; ++ni)
#pragma unroll
                        for (int r = 0; r < 4; ++r)
                            el[(mi * 16 + (lane >> 4) * 4 + r) * 256 +
                               wn * 64 + ni * 16 + (lane & 15)] = acc[mi][ni][r] * scale;
            }
            __builtin_amdgcn_s_barrier();
#pragma unroll
            for (int i = 0; i < 8; ++i) {
                const int cc  = i * 512 + tid;
                const int row = cc >> 6;
                const int c4  = (cc & 63) * 4;
                *(float4*)&C[(long)(gm + h * 64 + row) * ldC + gn + c4] =
                    *(const float4*)&el[row * 256 + c4];
            }
            __builtin_amdgcn_s_barrier();
        }
    }
}

template <int OUT_BF16>
__global__ __launch_bounds__(512, 2)
void gemm3b(const ushort_t* __restrict__ A, const ushort_t* __restrict__ B,
            void* __restrict__ Cout, int ldA, int ldB, int ldC,
            long sA, long sB, long sC, float scale,
            int n0, int n1, int xfirst)
{
    __shared__ ushort_t lds[3 * 24576];
    const int total = gridDim.x;
    const int lin   = blockIdx.x;
    const int swz   = (lin & 7) * (total >> 3) + (lin >> 3);
    const int c0    = swz % n0;
    const int rem   = swz / n0;
    const int c1    = rem % n1;
    const int bz    = rem / n1;
    const int bx    = xfirst ? c0 : c1;
    const int by    = xfirst ? c1 : c0;
    void* Cb = OUT_BF16 ? (void*)((ushort_t*)Cout + (long)bz * sC)
                        : (void*)((float*)Cout + (long)bz * sC);
    g3b_body<OUT_BF16>(A + (long)bz * sA, B + (long)bz * sB, Cb,
                       ldA, ldB, ldC, scale, bx, by, lds);
}

// ---------------------------------------------------------------------------
// 256x256 8-phase GEMM body (verified round-4): BK=64, 8 waves 2Mx4N,
// per-wave 128x64, 2 LDS bufs, counted vmcnt(8).
// ---------------------------------------------------------------------------
template <int OUT_BF16>
DI void g256_body(const ushort_t* __restrict__ Ab, const ushort_t* __restrict__ Bb,
                  void* __restrict__ Cb, int ldA, int ldB, int ldC,
                  float scale, int bx, int by, ushort_t* ldsp)
{
    constexpr int BUF   = 32768;
    constexpr int B_OFF = 16384;

    const int tid  = threadIdx.x;
    const int wave = tid >> 6;
    const int lane = tid & 63;
    const int wm   = wave >> 2;
    const int wn   = wave & 3;
    const int gm   = bx * 256;
    const int gn   = by * 256;

    const int srow = tid >> 3;
    const int scol = 8 * ((tid & 7) ^ (srow & 7));
    const int sdst = wave * 512;

    auto stage = [&](int t, int d, int op, int h) {
        const ushort_t* g  = op ? Bb : Ab;
        const int       ld = op ? ldB : ldA;
        const int       g0 = (op ? gn : gm) + h * 128;
#pragma unroll
        for (int j = 0; j < 2; ++j) {
            const ushort_t* src = g + (long)(g0 + j * 64 + srow) * ld + t * 64 + scol;
            __builtin_amdgcn_global_load_lds(
                (const __attribute__((address_space(1))) void*)src,
                (__attribute__((address_space(3))) void*)
                    (&ldsp[d * BUF + op * B_OFF + h * 8192 + j * 4096 + sdst]),
                16, 0, 0);
        }
    };

    const int arow = wm * 128 + (lane & 15);
    const int brow = wn * 64 + (lane & 15);
    const int cs0 = (((lane >> 4) * 16) ^ ((lane & 7) << 4)) >> 1;
    const int cs1 = ((64 + (lane >> 4) * 16) ^ ((lane & 7) << 4)) >> 1;

    f32x4 acc[8][4];
#pragma unroll
    for (int m = 0; m < 8; ++m)
#pragma unroll
        for (int n = 0; n < 4; ++n) acc[m][n] = (f32x4){0.f, 0.f, 0.f, 0.f};

    stage(0, 0, 0, 0); stage(0, 0, 0, 1); stage(0, 0, 1, 0); stage(0, 0, 1, 1);
    stage(1, 1, 0, 0); stage(1, 1, 0, 1); stage(1, 1, 1, 0); stage(1, 1, 1, 1);
    asm volatile("s_waitcnt vmcnt(8)" ::: "memory");
    __builtin_amdgcn_s_barrier();
    __builtin_amdgcn_sched_barrier(0);

    bf16x8 a[2][4], b0[2][2], b1[2][2];
#pragma unroll 2
    for (int t = 0; t < 16; ++t) {
        const int cur = t & 1;
        const ushort_t* la = &ldsp[cur * BUF];
        const ushort_t* lb = &ldsp[cur * BUF + B_OFF];

        // ph1
#pragma unroll
        for (int mi = 0; mi < 4; ++mi) {
            a[0][mi] = *(const bf16x8*)&la[(arow + mi * 16) * 64 + cs0];
            a[1][mi] = *(const bf16x8*)&la[(arow + mi * 16) * 64 + cs1];
        }
#pragma unroll
        for (int ni = 0; ni < 2; ++ni) {
            b0[0][ni] = *(const bf16x8*)&lb[(brow + ni * 16) * 64 + cs0];
            b0[1][ni] = *(const bf16x8*)&lb[(brow + ni * 16) * 64 + cs1];
        }
        __builtin_amdgcn_s_barrier();
        asm volatile("s_waitcnt lgkmcnt(0)" ::: "memory");
        __builtin_amdgcn_sched_barrier(0);
        __builtin_amdgcn_s_setprio(1);
#pragma unroll
        for (int mi = 0; mi < 4; ++mi)
#pragma unroll
            for (int ni = 0; ni < 2; ++ni) {
                acc[mi][ni] = __builtin_amdgcn_mfma_f32_16x16x32_bf16(a[0][mi], b0[0][ni], acc[mi][ni], 0, 0, 0);
                acc[mi][ni] = __builtin_amdgcn_mfma_f32_16x16x32_bf16(a[1][mi], b0[1][ni], acc[mi][ni], 0, 0, 0);
            }
        __builtin_amdgcn_s_setprio(0);
        __builtin_amdgcn_s_barrier();
        __builtin_amdgcn_sched_barrier(0);

        // ph2
#pragma unroll
        for (int ni = 0; ni < 2; ++ni) {
            b1[0][ni] = *(const bf16x8*)&lb[(brow + (ni + 2) * 16) * 64 + cs0];
            b1[1][ni] = *(const bf16x8*)&lb[(brow + (ni + 2) * 16) * 64 + cs1];
        }
        __builtin_amdgcn_s_barrier();
        asm volatile("s_waitcnt lgkmcnt(0)" ::: "memory");
        __builtin_amdgcn_sched_barrier(0);
        __builtin_amdgcn_s_setprio(1);
#pragma unroll
        for (int mi = 0; mi < 4; ++mi)
#pragma unroll
            for (int ni = 0; ni < 2; ++ni) {
                acc[mi][ni + 2] = __builtin_amdgcn_mfma_f32_16x16x32_bf16(a[0][mi], b1[0][ni], acc[mi][ni + 2], 0, 0, 0);
                acc[mi][ni + 2] = __builtin_amdgcn_mfma_f32_16x16x32_bf16(a[1][mi], b1[1][ni], acc[mi][ni + 2], 0, 0, 0);
            }
        __builtin_amdgcn_s_setprio(0);
        __builtin_amdgcn_s_barrier();
        __builtin_amdgcn_sched_barrier(0);

        // ph3
#pragma unroll
        for (int mi = 0; mi < 4; ++mi) {
            a[0][mi] = *(const bf16x8*)&la[(arow + (mi + 4) * 16) * 64 + cs0];
            a[1][mi] = *(const bf16x8*)&la[(arow + (mi + 4) * 16) * 64 + cs1];
        }
        if (t < 14) { stage(t + 2, cur, 1, 0); stage(t + 2, cur, 1, 1); }
        __builtin_amdgcn_s_barrier();
        asm volatile("s_waitcnt lgkmcnt(0)" ::: "memory");
        __builtin_amdgcn_sched_barrier(0);
        __builtin_amdgcn_s_setprio(1);
#pragma unroll
        for (int mi = 0; mi < 4; ++mi)
#pragma unroll
            for (int ni = 0; ni < 2; ++ni) {
                acc[mi + 4][ni + 2] = __builtin_amdgcn_mfma_f32_16x16x32_bf16(a[0][mi], b1[0][ni], acc[mi + 4][ni + 2], 0, 0, 0);
                acc[mi + 4][ni + 2] = __builtin_amdgcn_mfma_f32_16x16x32_bf16(a[1][mi], b1[1][ni], acc[mi + 4][ni + 2], 0, 0, 0);
            }
        __builtin_amdgcn_s_setprio(0);
        __builtin_amdgcn_s_barrier();
        __builtin_amdgcn_sched_barrier(0);

        // ph4
        if (t < 14) { stage(t + 2, cur, 0, 0); stage(t + 2, cur, 0, 1); }
        if (t < 14)       asm volatile("s_waitcnt vmcnt(8)" ::: "memory");
        else if (t == 14) asm volatile("s_waitcnt vmcnt(0)" ::: "memory");
        __builtin_amdgcn_sched_barrier(0);
        __builtin_amdgcn_s_setprio(1);
#pragma unroll
        for (int mi = 0; mi < 4; ++mi)
#pragma unroll
            for (int ni = 0; ni < 2; ++ni) {
                acc[mi + 4][ni] = __builtin_amdgcn_mfma_f32_16x16x32_bf16(a[0][mi], b0[0][ni], acc[mi + 4][ni], 0, 0, 0);
                acc[mi + 4][ni] = __builtin_amdgcn_mfma_f32_16x16x32_bf16(a[1][mi], b0[1][ni], acc[mi + 4][ni], 0, 0, 0);
            }
        __builtin_amdgcn_s_setprio(0);
        __builtin_amdgcn_s_barrier();
        __builtin_amdgcn_sched_barrier(0);
    }

    if (OUT_BF16) {
        ushort_t* el = ldsp;
#pragma unroll
        for (int mi = 0; mi < 8; ++mi)
#pragma unroll
            for (int ni = 0; ni < 4; ++ni)
#pragma unroll
                for (int r = 0; r < 4; ++r)
                    el[(wm * 128 + mi * 16 + (lane >> 4) * 4 + r) * 256 +
                       wn * 64 + ni * 16 + (lane & 15)] = f2bf(acc[mi][ni][r] * scale);
        __builtin_amdgcn_s_barrier();
        ushort_t* C = (ushort_t*)Cb;
#pragma unroll
        for (int i = 0; i < 16; ++i) {
            const int cc  = i * 512 + tid;
            const int row = cc >> 5;
            const int col = (cc & 31) * 8;
            *(bf16x8*)&C[(long)(gm + row) * ldC + gn + col] =
                *(const bf16x8*)&el[row * 256 + col];
        }
    } else {
        float* el = (float*)ldsp;
        float* C  = (float*)Cb;
#pragma unroll
        for (int h = 0; h < 2; ++h) {
            if (wm == h) {
#pragma unroll
                for (int mi = 0; mi < 8; ++mi)
#pragma unroll
                    for (int ni = 0; ni < 4; ++ni)
#pragma unroll
                        for (int r = 0; r < 4; ++r)
                            el[(mi * 16 + (lane >> 4) * 4 + r) * 256 +
                               wn * 64 + ni * 16 + (lane & 15)] = acc[mi][ni][r] * scale;
            }
            __builtin_amdgcn_s_barrier();
#pragma unroll
            for (int i = 0; i < 16; ++i) {
                const int cc  = i * 512 + tid;
                const int row = cc >> 6;
                const int c4  = (cc & 63) * 4;
                *(float4*)&C[(long)(gm + h * 128 + row) * ldC + gn + c4] =
                    *(const float4*)&el[row * 256 + c4];
            }
            __builtin_amdgcn_s_barrier();
        }
    }
}

// ---------------------------------------------------------------------------
// prep_g: 256 blocks x 512 thr (exactly 1 block/CU), ~20.5 KB LDS.
//   blocks 0..159:  x -> bf16 + sigma + prior rowsum (wave/row, stride 1280)
//   blocks 160..191: WvT transpose, 8 64x64 tiles each
//   blocks 192..255: G = Wk * Wq^T, f32 inputs, 2-deep reg-prefetch pipeline
// ---------------------------------------------------------------------------
__global__ __launch_bounds__(512)
void prep_g(const float* __restrict__ x, const float* __restrict__ Ws,
            const float* __restrict__ Wq, const float* __restrict__ Wk,
            const float* __restrict__ Wv,
            ushort_t* __restrict__ xh, float* __restrict__ sigma,
            float* __restrict__ rowsum,
            ushort_t* __restrict__ WvT, ushort_t* __restrict__ G)
{
    __shared__ char smem[20608];
    const int blk = blockIdx.x;
    const int tid = threadIdx.x;

    if (blk < 160) {
        const int wave = tid >> 6, lane = tid & 63;
        for (int row = blk * 8 + wave; row < 8192; row += 1280) {
            const float* xr = x + (long)row * 1024;
            float dot = 0.f;
#pragma unroll
            for (int c = 0; c < 4; ++c) {
                const int i = c * 256 + lane * 4;
                float4 v = *(const float4*)(xr + i);
                float4 w = *(const float4*)(Ws + i);
                dot += v.x * w.x + v.y * w.y + v.z * w.z + v.w * w.w;
                ushort4 o;
                o.x = f2bf(v.x); o.y = f2bf(v.y); o.z = f2bf(v.z); o.w = f2bf(v.w);
                *(ushort4*)(xh + (long)row * 1024 + i) = o;
            }
#pragma unroll
            for (int o = 32; o; o >>= 1) dot += __shfl_down(dot, o);
            float sg;
            if (lane == 0) {
                float s = 1.f / (1.f + __expf(-5.f * dot)) + 1e-5f;
                sg = exp2f(s * 1.5849625007211562f) - 1.f;   // 3^s - 1
            }
            sg = __shfl(sg, 0);
            const int i = row & 1023;
            const float c = -0.5f / (sg * sg);
            float a = 0.f;
            for (int j = lane; j < 1024; j += 64) {
                float d = (float)(i - j);
                a += __expf(c * d * d);
            }
#pragma unroll
            for (int o = 32; o; o >>= 1) a += __shfl_down(a, o);
            if (lane == 0) {
                sigma[row]  = sg;
                rowsum[row] = (0.3989422804014327f / sg) * a;
            }
        }
    } else if (blk < 192) {
        float (*s)[65] = (float(*)[65])smem;
        const int r = tid >> 4, c4 = (tid & 15) * 4;   // r: 0..31
#pragma unroll
        for (int it = 0; it < 8; ++it) {
            const int tile = (blk - 160) * 8 + it;
            const int tr = (tile >> 4) * 64, tc = (tile & 15) * 64;
#pragma unroll
            for (int rr = r; rr < 64; rr += 32) {
                float4 v = *(const float4*)(Wv + (long)(tr + rr) * 1024 + tc + c4);
                s[rr][c4] = v.x; s[rr][c4 + 1] = v.y; s[rr][c4 + 2] = v.z; s[rr][c4 + 3] = v.w;
            }
            __syncthreads();
#pragma unroll
            for (int rr = r; rr < 64; rr += 32) {
                ushort4 o;
                o.x = f2bf(s[c4][rr]);     o.y = f2bf(s[c4 + 1][rr]);
                o.z = f2bf(s[c4 + 2][rr]); o.w = f2bf(s[c4 + 3][rr]);
                *(ushort4*)(WvT + (long)(tc + rr) * 1024 + tr + c4) = o;
            }
            __syncthreads();
        }
    } else {
        // G = Wk * Wq^T (bf16 out), 128x128 tile, K=1024, BK=32,
        // 8 waves (2M x 4N), per-wave 64x32 = acc[4][2].
        // LDS [128][40] ushort per operand; 2-deep register prefetch:
        // set A holds tile k (even), set B tile k+1 (odd); loads for k+2
        // issued while k computes -> ~2 half-iters (~700cy) to land.
        ushort_t* sA = (ushort_t*)smem;          // 5120 ushorts
        ushort_t* sB = sA + 5120;
        const int g  = blk - 192;                // 0..63
        const int gm = (g >> 3) * 128, gn = (g & 7) * 128;
        const int wave = tid >> 6, lane = tid & 63;
        const int wm = wave >> 2, wn = wave & 3;
        const int lrow = tid >> 3, lcol = (tid & 7) * 4;   // 64 rows/pass
        const float* A0 = Wk + (long)(gm + lrow) * 1024 + lcol;
        const float* A1 = Wk + (long)(gm + 64 + lrow) * 1024 + lcol;
        const float* B0 = Wq + (long)(gn + lrow) * 1024 + lcol;
        const float* B1 = Wq + (long)(gn + 64 + lrow) * 1024 + lcol;

        f32x4 acc[4][2];
#pragma unroll
        for (int m = 0; m < 4; ++m)
#pragma unroll
            for (int n = 0; n < 2; ++n) acc[m][n] = (f32x4){0.f, 0.f, 0.f, 0.f};

        auto wr = [&](float4 a0, float4 a1, float4 b0, float4 b1) {
            ushort4 o;
            o.x = f2bf(a0.x); o.y = f2bf(a0.y); o.z = f2bf(a0.z); o.w = f2bf(a0.w);
            *(ushort4*)&sA[lrow * 40 + lcol] = o;
            o.x = f2bf(a1.x); o.y = f2bf(a1.y); o.z = f2bf(a1.z); o.w = f2bf(a1.w);
            *(ushort4*)&sA[(64 + lrow) * 40 + lcol] = o;
            o.x = f2bf(b0.x); o.y = f2bf(b0.y); o.z = f2bf(b0.z); o.w = f2bf(b0.w);
            *(ushort4*)&sB[lrow * 40 + lcol] = o;
            o.x = f2bf(b1.x); o.y = f2bf(b1.y); o.z = f2bf(b1.z); o.w = f2bf(b1.w);
            *(ushort4*)&sB[(64 + lrow) * 40 + lcol] = o;
        };
        auto mm = [&]() {
            bf16x8 af[4], bfv[2];
#pragma unroll
            for (int mi = 0; mi < 4; ++mi)
                af[mi] = *(const bf16x8*)&sA[(wm * 64 + mi * 16 + (lane & 15)) * 40 + (lane >> 4) * 8];
#pragma unroll
            for (int ni = 0; ni < 2; ++ni)
                bfv[ni] = *(const bf16x8*)&sB[(wn * 32 + ni * 16 + (lane & 15)) * 40 + (lane >> 4) * 8];
#pragma unroll
            for (int mi = 0; mi < 4; ++mi)
#pragma unroll
                for (int ni = 0; ni < 2; ++ni)
                    acc[mi][ni] = __builtin_amdgcn_mfma_f32_16x16x32_bf16(af[mi], bfv[ni], acc[mi][ni], 0, 0, 0);
        };

        // prologue: tile0 -> set A, tile1 -> set B
        float4 a0A = *(const float4*)(A0);      float4 a1A = *(const float4*)(A1);
        float4 b0A = *(const float4*)(B0);      float4 b1A = *(const float4*)(B1);
        float4 a0B = *(const float4*)(A0 + 32); float4 a1B = *(const float4*)(A1 + 32);
        float4 b0B = *(const float4*)(B0 + 32); float4 b1B = *(const float4*)(B1 + 32);

        for (int k0 = 0; k0 < 1024; k0 += 64) {
            // even tile (k0): set A
            wr(a0A, a1A, b0A, b1A);
            if (k0 < 960) {
                a0A = *(const float4*)(A0 + k0 + 64); a1A = *(const float4*)(A1 + k0 + 64);
                b0A = *(const float4*)(B0 + k0 + 64); b1A = *(const float4*)(B1 + k0 + 64);
            }
            __syncthreads();
            mm();
            __syncthreads();
            // odd tile (k0+32): set B
            wr(a0B, a1B, b0B, b1B);
            if (k0 < 928) {
                a0B = *(const float4*)(A0 + k0 + 96); a1B = *(const float4*)(A1 + k0 + 96);
                b0B = *(const float4*)(B0 + k0 + 96); b1B = *(const float4*)(B1 + k0 + 96);
            }
            __syncthreads();
            mm();
            __syncthreads();
        }
        // C/D layout: col = lane&15, row = (lane>>4)*4 + r
#pragma unroll
        for (int mi = 0; mi < 4; ++mi)
#pragma unroll
            for (int ni = 0; ni < 2; ++ni)
#pragma unroll
                for (int r = 0; r < 4; ++r)
                    G[(long)(gm + wm * 64 + mi * 16 + (lane >> 4) * 4 + r) * 1024 +
                      gn + wn * 32 + ni * 16 + (lane & 15)] = f2bf(acc[mi][ni][r]);
    }
}

// ---------------------------------------------------------------------------
// sc_vt: 256 blocks x 512 thr, 128 KB LDS (one residency round).
//   lin 0..127:   scores_b = xq_b * x_b^T / 32 (f32 -> Pout scratch), b = lin&7
//   lin 128..255: VT = Wv^T x^T (bf16, ld 8192)
// ---------------------------------------------------------------------------
__global__ __launch_bounds__(512, 2)
void sc_vt(const ushort_t* __restrict__ xqh, const ushort_t* __restrict__ xh,
           float* __restrict__ scores,
           const ushort_t* __restrict__ WvT, ushort_t* __restrict__ VTall)
{
    __shared__ ushort_t lds[2 * 32768];
    const int lin = blockIdx.x;
    if (lin < 128) {
        const int bz = lin & 7;
        const int t  = lin >> 3;           // 0..15
        g256_body<0>(xqh + (long)bz * ND, xh + (long)bz * ND,
                     (void*)(scores + (long)bz * NN),
                     1024, 1024, 1024, 0.03125f, t & 3, t >> 2, lds);
    } else {
        const int l  = lin - 128;
        const int l2 = (l & 7) * 16 + (l >> 3);   // chunked per XCD
        g256_body<1>(WvT, xh, (void*)VTall,
                     1024, 1024, 8192, 1.f, l2 & 3, l2 >> 2, lds);
    }
}

// ---------------------------------------------------------------------------
// sv_prior: 256 blocks x 512 thr, 128 KB LDS (one residency round).
//   lin 0..127:   Z_b = S_b * V_b (f32), b = lin&7
//   lin 128..255: prior P write; each block derives batchsum from rowsum
// ---------------------------------------------------------------------------
__global__ __launch_bounds__(512, 2)
void sv_prior(const ushort_t* __restrict__ S, const ushort_t* __restrict__ VTall,
              float* __restrict__ Z, const float* __restrict__ sigma,
              const float* __restrict__ rowsum, float* __restrict__ P)
{
    __shared__ ushort_t lds[2 * 32768];
    const int lin = blockIdx.x;
    const int tid = threadIdx.x;
    if (lin < 128) {
        const int bz = lin & 7;
        const int t  = lin >> 3;
        g256_body<0>(S + (long)bz * NN, VTall + bz * 1024,
                     (void*)(Z + (long)bz * ND),
                     1024, 8192, 1024, 1.f, t & 3, t >> 2, lds);
    } else {
        const int l = lin - 128;           // 0..127
        const int b = l >> 4;              // 16 blocks per batch
        float* sred = (float*)lds;
        float a = rowsum[b * 1024 + tid] + rowsum[b * 1024 + 512 + tid];
        sred[tid] = a; __syncthreads();
        for (int o = 256; o; o >>= 1) { if (tid < o) sred[tid] += sred[tid + o]; __syncthreads(); }
        const float bs = sred[0];
        const int r0 = (l & 15) * 64;      // 64 rows per block
#pragma unroll
        for (int it = 0; it < 32; ++it) {
            const int e   = it * 512 + tid;        // 0..16383
            const int row = r0 + (e >> 8);
            const int j4  = (e & 255) * 4;
            const float sg  = sigma[(b << 10) + row];
            const float c   = -0.5f / (sg * sg);
            const float inv = 0.3989422804014327f / (sg * bs);
            float4 o;
            float d;
            d = (float)(row - j4);       o.x = inv * __expf(c * d * d);
            d = (float)(row - j4 - 1);   o.y = inv * __expf(c * d * d);
            d = (float)(row - j4 - 2);   o.z = inv * __expf(c * d * d);
            d = (float)(row - j4 - 3);   o.w = inv * __expf(c * d * d);
            *(float4*)&P[(long)b * NN + (long)row * 1024 + j4] = o;
        }
    }
}

// softmax over batch dim (8 values, stride NN)
__global__ void softmax_batch(const float* __restrict__ scores, ushort_t* __restrict__ S)
{
    const long idx = (long)blockIdx.x * 256 + threadIdx.x;
    float v[8], m = -1e30f;
#pragma unroll
    for (int b = 0; b < 8; ++b) { v[b] = scores[(long)b * NN + idx]; m = fmaxf(m, v[b]); }
    float sum = 0.f;
#pragma unroll
    for (int b = 0; b < 8; ++b) { v[b] = __expf(v[b] - m); sum += v[b]; }
    const float inv = 1.f / sum;
#pragma unroll
    for (int b = 0; b < 8; ++b) S[(long)b * NN + idx] = f2bf(v[b] * inv);
}

// ---------------------------------------------------------------------------
extern "C" void kernel_launch(void* const* d_in, const int* in_sizes, int n_in,
                              void* d_out, int out_size, void* d_ws, size_t ws_size,
                              hipStream_t stream)
{
    const float* x  = (const float*)d_in[0];
    const float* Wq = (const float*)d_in[1];
    const float* Wk = (const float*)d_in[2];
    const float* Wv = (const float*)d_in[3];
    const float* Ws = (const float*)d_in[4];
    float* Zout = (float*)d_out;
    float* Pout = Zout + 8 * ND;

    char* base = (char*)d_ws;
    size_t off = 0;
    auto alloc = [&](size_t bytes) {
        void* p = base + off;
        off = (off + bytes + 255) & ~(size_t)255;
        return p;
    };
    ushort_t* xh    = (ushort_t*)alloc(8192L * 1024 * 2);   // 16.78 MB
    ushort_t* G     = (ushort_t*)alloc(NN * 2);             //  2.10 MB
    ushort_t* WvT   = (ushort_t*)alloc(NN * 2);             //  2.10 MB
    ushort_t* xqh   = (ushort_t*)alloc(8192L * 1024 * 2);   // 16.78 MB
    ushort_t* VTall = (ushort_t*)alloc(1024L * 8192 * 2);   // 16.78 MB
    float* sigma    = (float*)alloc(8192 * 4);
    float* rowsum   = (float*)alloc(8192 * 4);
    // overlays: scores (f32) -> Pout (consumed by softmax before sv_prior's
    //           prior blocks overwrite it); S (bf16) -> xh (x-input dead
    //           after sc_vt)
    float*    scores = Pout;
    ushort_t* Sh     = xh;

    // 1. prep (x->bf16+sigma+rowsum | WvT) + G = Wk*Wq^T (pipelined)
    prep_g<<<256, 512, 0, stream>>>(x, Ws, Wq, Wk, Wv, xh, sigma, rowsum, WvT, G);
    // 2. xq = x * (Wq Wk^T)   (256 blocks, by-fastest XCD chunking)
    gemm3b<1><<<256, 512, 0, stream>>>(
        xh, G, xqh, 1024, 1024, 1024, 0, 0, 0, 1.f, 4, 64, 0);
    // 3. scores (128 @256^2, batch=XCD) | VT (128 @256^2, chunked)
    sc_vt<<<256, 512, 0, stream>>>(xqh, xh, scores, WvT, VTall);
    // 4. softmax over batch -> S (bf16, overlays xh)
    softmax_batch<<<4096, 256, 0, stream>>>(scores, Sh);
    // 5. Z = S V (128 @256^2, batch=XCD) | prior P write (128, own batchsum)
    sv_prior<<<256, 512, 0, stream>>>(Sh, VTall, Zout, sigma, rowsum, Pout);
}